// Round 1
// baseline (46216.275 us; speedup 1.0000x reference)
//
#include <hip/hip_runtime.h>
#include <math.h>

#define Dh 1024
#define Tt 4096
#define NB 128   // recurrence blocks; each owns 8 output columns

// ---------------------------------------------------------------------------
// GEMM: C[M x N](ldc) = op(A[M x K]) @ B[K x N] + bias [+ resid]
// 64x64 tile, BK=16, 256 threads, 4x4 micro-tile per thread. fp32.
// ---------------------------------------------------------------------------
template<bool RELU, bool RESID>
__global__ __launch_bounds__(256)
void gemm64(const float* __restrict__ A, const float* __restrict__ B,
            const float* __restrict__ bias, const float* __restrict__ resid,
            float* __restrict__ C, int M, int N, int K, int ldc)
{
    __shared__ __align__(16) float As[16][68];   // [k][m], padded row (272B, 16B-aligned)
    __shared__ __align__(16) float Bs[16][64];   // [k][n]
    const int tid = threadIdx.x;
    const int tx = tid & 15, ty = tid >> 4;
    const int bn = blockIdx.x * 64, bm = blockIdx.y * 64;

    const int lm = tid >> 2, lk = (tid & 3) * 4;     // A tile load coords
    const int bk = tid >> 4, bn4 = (tid & 15) * 4;   // B tile load coords

    float acc[4][4] = {};

    for (int k0 = 0; k0 < K; k0 += 16) {
        float4 av = *(const float4*)(A + (size_t)(bm + lm) * K + k0 + lk);
        if (RELU) {
            av.x = fmaxf(av.x, 0.f); av.y = fmaxf(av.y, 0.f);
            av.z = fmaxf(av.z, 0.f); av.w = fmaxf(av.w, 0.f);
        }
        As[lk + 0][lm] = av.x; As[lk + 1][lm] = av.y;
        As[lk + 2][lm] = av.z; As[lk + 3][lm] = av.w;
        *(float4*)&Bs[bk][bn4] = *(const float4*)(B + (size_t)(k0 + bk) * N + bn + bn4);
        __syncthreads();
        #pragma unroll
        for (int kk = 0; kk < 16; ++kk) {
            float4 a4 = *(const float4*)&As[kk][ty * 4];
            float4 b4 = *(const float4*)&Bs[kk][tx * 4];
            acc[0][0] += a4.x * b4.x; acc[0][1] += a4.x * b4.y; acc[0][2] += a4.x * b4.z; acc[0][3] += a4.x * b4.w;
            acc[1][0] += a4.y * b4.x; acc[1][1] += a4.y * b4.y; acc[1][2] += a4.y * b4.z; acc[1][3] += a4.y * b4.w;
            acc[2][0] += a4.z * b4.x; acc[2][1] += a4.z * b4.y; acc[2][2] += a4.z * b4.z; acc[2][3] += a4.z * b4.w;
            acc[3][0] += a4.w * b4.x; acc[3][1] += a4.w * b4.y; acc[3][2] += a4.w * b4.z; acc[3][3] += a4.w * b4.w;
        }
        __syncthreads();
    }

    const float4 bias4 = *(const float4*)(bias + bn + tx * 4);
    #pragma unroll
    for (int i = 0; i < 4; ++i) {
        const int row = bm + ty * 4 + i;
        float4 o;
        o.x = acc[i][0] + bias4.x; o.y = acc[i][1] + bias4.y;
        o.z = acc[i][2] + bias4.z; o.w = acc[i][3] + bias4.w;
        if (RESID) {
            const float4 r4 = *(const float4*)(resid + (size_t)row * N + bn + tx * 4);
            o.x += r4.x; o.y += r4.y; o.z += r4.z; o.w += r4.w;
        }
        *(float4*)(C + (size_t)row * ldc + bn + tx * 4) = o;
    }
}

// ---------------------------------------------------------------------------
// Sequential GRU scan. 128 blocks x 256 threads, all co-resident.
// Block b owns output columns [8b, 8b+8). Per column: one 32-lane group
// computes the 3 hidden-matvec dots (weights live in VGPRs: 96 floats/thread).
// Per step: all-gather h (4KB) via AGENT-scope loads; per-block release flag.
// ---------------------------------------------------------------------------
__global__ __launch_bounds__(256)
void gru_rec(const float* __restrict__ xproj,   // [T][3*Dh]  (r,z,n) incl. input bias
             const float* __restrict__ h0src,   // [Dh] init_state
             const float* __restrict__ Whr, const float* __restrict__ Whz,
             const float* __restrict__ Whn, const float* __restrict__ bhn,
             float* __restrict__ ys,            // [T][Dh]
             float* __restrict__ hbuf,          // [2][Dh] ping-pong
             unsigned int* __restrict__ flags)  // [NB], zeroed before launch
{
    const int b = blockIdx.x, tid = threadIdx.x;
    const int g = tid >> 5;        // group 0..7 -> local column
    const int i = tid & 31;        // lane in group
    const int col = b * 8 + g;

    __shared__ __align__(16) float h_lds[Dh];

    // Load this thread's weight slice into registers: rows r = 4i + 128j + k
    float wr[32], wz[32], wn[32];
    #pragma unroll
    for (int j = 0; j < 8; ++j)
        #pragma unroll
        for (int k = 0; k < 4; ++k) {
            const int r = 4 * i + 128 * j + k;
            wr[j * 4 + k] = Whr[(size_t)r * Dh + col];
            wz[j * 4 + k] = Whz[(size_t)r * Dh + col];
            wn[j * 4 + k] = Whn[(size_t)r * Dh + col];
        }
    const float bhn_c = bhn[col];

    float* hA = hbuf;          // dest for even t
    float* hB = hbuf + Dh;     // dest for odd t

    for (int t = 0; t < Tt; ++t) {
        // stage h_{t-1} into LDS (AGENT loads bypass stale L1/L2 across XCDs)
        const float* hsrc = (t == 0) ? h0src : ((t & 1) ? hA : hB);
        #pragma unroll
        for (int j = 0; j < 4; ++j) {
            const int idx = tid + j * 256;
            h_lds[idx] = __hip_atomic_load((const float*)(hsrc + idx),
                                           __ATOMIC_RELAXED, __HIP_MEMORY_SCOPE_AGENT);
        }
        __syncthreads();

        float ar = 0.f, az = 0.f, an = 0.f;
        const float4* h4 = (const float4*)h_lds;
        #pragma unroll
        for (int j = 0; j < 8; ++j) {
            const float4 hv = h4[i + j * 32];
            ar += hv.x * wr[4*j] + hv.y * wr[4*j+1] + hv.z * wr[4*j+2] + hv.w * wr[4*j+3];
            az += hv.x * wz[4*j] + hv.y * wz[4*j+1] + hv.z * wz[4*j+2] + hv.w * wz[4*j+3];
            an += hv.x * wn[4*j] + hv.y * wn[4*j+1] + hv.z * wn[4*j+2] + hv.w * wn[4*j+3];
        }
        #pragma unroll
        for (int off = 16; off > 0; off >>= 1) {
            ar += __shfl_down(ar, off, 32);
            az += __shfl_down(az, off, 32);
            an += __shfl_down(an, off, 32);
        }

        if (i == 0) {
            const float* xp = xproj + (size_t)t * (3 * Dh);
            const float xr = xp[col], xz = xp[Dh + col], xn = xp[2 * Dh + col];
            const float r = 1.f / (1.f + expf(-(xr + ar)));
            const float z = 1.f / (1.f + expf(-(xz + az)));
            const float n = tanhf(xn + r * (an + bhn_c));
            const float hp = h_lds[col];
            const float hnew = (1.f - z) * n + z * hp;
            float* hdst = (t & 1) ? hB : hA;
            __hip_atomic_store(hdst + col, hnew, __ATOMIC_RELAXED, __HIP_MEMORY_SCOPE_AGENT);
            ys[(size_t)t * Dh + col] = hnew;
        }
        __syncthreads();                       // (A) all stores issued, LDS reads done

        if (tid == 0) {
            __threadfence();                   // device-scope release of h stores
            __hip_atomic_store(flags + b, (unsigned int)(t + 1),
                               __ATOMIC_RELEASE, __HIP_MEMORY_SCOPE_AGENT);
        }
        if (tid < NB) {                        // wait for every producer's step-t flag
            while (__hip_atomic_load((const unsigned int*)(flags + tid),
                                     __ATOMIC_ACQUIRE, __HIP_MEMORY_SCOPE_AGENT)
                   < (unsigned int)(t + 1)) {}
        }
        __syncthreads();                       // (B)
    }
}

// ---------------------------------------------------------------------------
// In-place layernorm over rows of y [T][Dh], matching jnp mean/var, eps=1e-6
// ---------------------------------------------------------------------------
__global__ __launch_bounds__(256)
void layernorm_ip(float* __restrict__ y, const float* __restrict__ sc,
                  const float* __restrict__ bi)
{
    __shared__ float red[8], red2[8], stat[2];
    const int row = blockIdx.x, tid = threadIdx.x;
    float4* yr = (float4*)(y + (size_t)row * Dh);
    float4 v = yr[tid];
    float s  = v.x + v.y + v.z + v.w;
    float s2 = v.x*v.x + v.y*v.y + v.z*v.z + v.w*v.w;
    #pragma unroll
    for (int off = 32; off > 0; off >>= 1) {
        s  += __shfl_down(s,  off);
        s2 += __shfl_down(s2, off);
    }
    if ((tid & 63) == 0) { red[tid >> 6] = s; red2[tid >> 6] = s2; }
    __syncthreads();
    if (tid == 0) {
        float ts = 0.f, t2 = 0.f;
        #pragma unroll
        for (int w = 0; w < 4; ++w) { ts += red[w]; t2 += red2[w]; }
        const float mu  = ts / (float)Dh;
        const float var = t2 / (float)Dh - mu * mu;
        stat[0] = mu;
        stat[1] = rsqrtf(var + 1e-6f);
    }
    __syncthreads();
    const float mu = stat[0], rstd = stat[1];
    const float4 s4 = ((const float4*)sc)[tid];
    const float4 b4 = ((const float4*)bi)[tid];
    v.x = (v.x - mu) * rstd * s4.x + b4.x;
    v.y = (v.y - mu) * rstd * s4.y + b4.y;
    v.z = (v.z - mu) * rstd * s4.z + b4.z;
    v.w = (v.w - mu) * rstd * s4.w + b4.w;
    yr[tid] = v;
}

// ---------------------------------------------------------------------------
extern "C" void kernel_launch(void* const* d_in, const int* in_sizes, int n_in,
                              void* d_out, int out_size, void* d_ws, size_t ws_size,
                              hipStream_t stream)
{
    const float* xs   = (const float*)d_in[0];
    const float* h0   = (const float*)d_in[1];
    const float* Wir  = (const float*)d_in[2];
    const float* Wiz  = (const float*)d_in[3];
    const float* Win  = (const float*)d_in[4];
    const float* bir  = (const float*)d_in[5];
    const float* biz  = (const float*)d_in[6];
    const float* bin_ = (const float*)d_in[7];
    const float* Whr  = (const float*)d_in[8];
    const float* Whz  = (const float*)d_in[9];
    const float* Whn  = (const float*)d_in[10];
    const float* bhn  = (const float*)d_in[11];
    const float* Wl   = (const float*)d_in[12];
    const float* bl   = (const float*)d_in[13];
    const float* ln_s = (const float*)d_in[14];
    const float* ln_b = (const float*)d_in[15];
    float* out = (float*)d_out;

    // workspace layout
    float* xproj = (float*)d_ws;                               // T*3*Dh
    float* ys    = xproj + (size_t)Tt * 3 * Dh;                // T*Dh
    float* hbuf  = ys + (size_t)Tt * Dh;                       // 2*Dh
    unsigned int* flags = (unsigned int*)(hbuf + 2 * Dh);      // NB

    hipMemsetAsync(flags, 0, NB * sizeof(unsigned int), stream);

    // Phase 1: input projections (bias folded in)
    dim3 ggrid(Dh / 64, Tt / 64);
    gemm64<false, false><<<ggrid, 256, 0, stream>>>(xs, Wir, bir, nullptr,
                                                    xproj + 0 * Dh, Tt, Dh, Dh, 3 * Dh);
    gemm64<false, false><<<ggrid, 256, 0, stream>>>(xs, Wiz, biz, nullptr,
                                                    xproj + 1 * Dh, Tt, Dh, Dh, 3 * Dh);
    gemm64<false, false><<<ggrid, 256, 0, stream>>>(xs, Win, bin_, nullptr,
                                                    xproj + 2 * Dh, Tt, Dh, Dh, 3 * Dh);

    // Phase 2: sequential scan (persistent, co-resident grid)
    gru_rec<<<NB, 256, 0, stream>>>(xproj, h0, Whr, Whz, Whn, bhn, ys, hbuf, flags);

    // Phase 3: out = relu(ys) @ Wl + bl + xs, then in-place layernorm
    gemm64<true, true><<<ggrid, 256, 0, stream>>>(ys, Wl, bl, xs, out, Tt, Dh, Dh, Dh);
    layernorm_ip<<<Tt, 256, 0, stream>>>(out, ln_s, ln_b);
}

// Round 2
// 11573.222 us; speedup vs baseline: 3.9934x; 3.9934x over previous
//
#include <hip/hip_runtime.h>
#include <math.h>

#define Dh 1024
#define Tt 4096
#define NB 128   // recurrence blocks; each owns 8 output columns

// ---------------------------------------------------------------------------
// GEMM: C[M x N](ldc) = op(A[M x K]) @ B[K x N] + bias [+ resid]
// 64x64 tile, BK=16, 256 threads, 4x4 micro-tile per thread. fp32.
// ---------------------------------------------------------------------------
template<bool RELU, bool RESID>
__global__ __launch_bounds__(256)
void gemm64(const float* __restrict__ A, const float* __restrict__ B,
            const float* __restrict__ bias, const float* __restrict__ resid,
            float* __restrict__ C, int M, int N, int K, int ldc)
{
    __shared__ __align__(16) float As[16][68];   // [k][m], padded row
    __shared__ __align__(16) float Bs[16][64];   // [k][n]
    const int tid = threadIdx.x;
    const int tx = tid & 15, ty = tid >> 4;
    const int bn = blockIdx.x * 64, bm = blockIdx.y * 64;

    const int lm = tid >> 2, lk = (tid & 3) * 4;     // A tile load coords
    const int bk = tid >> 4, bn4 = (tid & 15) * 4;   // B tile load coords

    float acc[4][4] = {};

    for (int k0 = 0; k0 < K; k0 += 16) {
        float4 av = *(const float4*)(A + (size_t)(bm + lm) * K + k0 + lk);
        if (RELU) {
            av.x = fmaxf(av.x, 0.f); av.y = fmaxf(av.y, 0.f);
            av.z = fmaxf(av.z, 0.f); av.w = fmaxf(av.w, 0.f);
        }
        As[lk + 0][lm] = av.x; As[lk + 1][lm] = av.y;
        As[lk + 2][lm] = av.z; As[lk + 3][lm] = av.w;
        *(float4*)&Bs[bk][bn4] = *(const float4*)(B + (size_t)(k0 + bk) * N + bn + bn4);
        __syncthreads();
        #pragma unroll
        for (int kk = 0; kk < 16; ++kk) {
            float4 a4 = *(const float4*)&As[kk][ty * 4];
            float4 b4 = *(const float4*)&Bs[kk][tx * 4];
            acc[0][0] += a4.x * b4.x; acc[0][1] += a4.x * b4.y; acc[0][2] += a4.x * b4.z; acc[0][3] += a4.x * b4.w;
            acc[1][0] += a4.y * b4.x; acc[1][1] += a4.y * b4.y; acc[1][2] += a4.y * b4.z; acc[1][3] += a4.y * b4.w;
            acc[2][0] += a4.z * b4.x; acc[2][1] += a4.z * b4.y; acc[2][2] += a4.z * b4.z; acc[2][3] += a4.z * b4.w;
            acc[3][0] += a4.w * b4.x; acc[3][1] += a4.w * b4.y; acc[3][2] += a4.w * b4.z; acc[3][3] += a4.w * b4.w;
        }
        __syncthreads();
    }

    const float4 bias4 = *(const float4*)(bias + bn + tx * 4);
    #pragma unroll
    for (int i = 0; i < 4; ++i) {
        const int row = bm + ty * 4 + i;
        float4 o;
        o.x = acc[i][0] + bias4.x; o.y = acc[i][1] + bias4.y;
        o.z = acc[i][2] + bias4.z; o.w = acc[i][3] + bias4.w;
        if (RESID) {
            const float4 r4 = *(const float4*)(resid + (size_t)row * N + bn + tx * 4);
            o.x += r4.x; o.y += r4.y; o.z += r4.z; o.w += r4.w;
        }
        *(float4*)(C + (size_t)row * ldc + bn + tx * 4) = o;
    }
}

// ---------------------------------------------------------------------------
// Pack init_state into epoch-tagged slots: {tag=0 : value} in buf[0]
// ---------------------------------------------------------------------------
__global__ __launch_bounds__(256)
void pack_h0(const float* __restrict__ h0, unsigned long long* __restrict__ buf)
{
    const int idx = blockIdx.x * 256 + threadIdx.x;   // 0..1023
    // tag 0 in high 32 bits
    __hip_atomic_store(buf + idx, (unsigned long long)__float_as_uint(h0[idx]),
                       __ATOMIC_RELAXED, __HIP_MEMORY_SCOPE_AGENT);
}

// ---------------------------------------------------------------------------
// Sequential GRU scan. 128 blocks x 256 threads, all co-resident.
// Block b owns output columns [8b, 8b+8); each column = one 32-lane group.
// Weights register-resident (96 floats/thread, launch_bounds(256,1)).
// Sync: h entries are {tag,value} 64-bit atomics — consumers poll tags
// directly; no fences, no flags. Ping-pong buffers buf[t&1] -> buf[(t+1)&1].
// ---------------------------------------------------------------------------
__global__ __launch_bounds__(256, 1)
void gru_rec(const float* __restrict__ xproj,   // [T][3*Dh]  (r,z,n) incl. input bias
             const float* __restrict__ Whr, const float* __restrict__ Whz,
             const float* __restrict__ Whn, const float* __restrict__ bhn,
             float* __restrict__ ys,            // [T][Dh]
             unsigned long long* __restrict__ hbuf)  // [2][Dh] packed {tag,val}
{
    const int b = blockIdx.x, tid = threadIdx.x;
    const int g = tid >> 5;        // group 0..7 -> local column
    const int i = tid & 31;        // lane in group
    const int col = b * 8 + g;

    __shared__ __align__(16) float h_lds[Dh];

    // Register-resident weight slice: rows r = 4i + 128j + k
    float wr[32], wz[32], wn[32];
    #pragma unroll
    for (int j = 0; j < 8; ++j)
        #pragma unroll
        for (int k = 0; k < 4; ++k) {
            const int r = 4 * i + 128 * j + k;
            wr[j * 4 + k] = Whr[(size_t)r * Dh + col];
            wz[j * 4 + k] = Whz[(size_t)r * Dh + col];
            wn[j * 4 + k] = Whn[(size_t)r * Dh + col];
        }
    const float bhn_c = bhn[col];

    for (int t = 0; t < Tt; ++t) {
        const unsigned long long* src = hbuf + (size_t)(t & 1) * Dh;
        unsigned long long*       dst = hbuf + (size_t)((t + 1) & 1) * Dh;
        const unsigned int want = (unsigned int)t;

        // prefetch this step's xproj entries (independent of h)
        float xr = 0.f, xz = 0.f, xn = 0.f;
        if (i == 0) {
            const float* xp = xproj + (size_t)t * (3 * Dh);
            xr = xp[col]; xz = xp[Dh + col]; xn = xp[2 * Dh + col];
        }

        // poll this thread's 4 packed entries until their tags reach t
        unsigned long long p0, p1, p2, p3;
        for (;;) {
            p0 = __hip_atomic_load(src + tid +   0, __ATOMIC_RELAXED, __HIP_MEMORY_SCOPE_AGENT);
            p1 = __hip_atomic_load(src + tid + 256, __ATOMIC_RELAXED, __HIP_MEMORY_SCOPE_AGENT);
            p2 = __hip_atomic_load(src + tid + 512, __ATOMIC_RELAXED, __HIP_MEMORY_SCOPE_AGENT);
            p3 = __hip_atomic_load(src + tid + 768, __ATOMIC_RELAXED, __HIP_MEMORY_SCOPE_AGENT);
            unsigned int bad = ((unsigned int)(p0 >> 32)) ^ want;
            bad |= ((unsigned int)(p1 >> 32)) ^ want;
            bad |= ((unsigned int)(p2 >> 32)) ^ want;
            bad |= ((unsigned int)(p3 >> 32)) ^ want;
            if (!bad) break;
            __builtin_amdgcn_s_sleep(1);
        }
        h_lds[tid +   0] = __uint_as_float((unsigned int)p0);
        h_lds[tid + 256] = __uint_as_float((unsigned int)p1);
        h_lds[tid + 512] = __uint_as_float((unsigned int)p2);
        h_lds[tid + 768] = __uint_as_float((unsigned int)p3);
        __syncthreads();

        float ar = 0.f, az = 0.f, an = 0.f;
        const float4* h4 = (const float4*)h_lds;
        #pragma unroll
        for (int j = 0; j < 8; ++j) {
            const float4 hv = h4[i + j * 32];
            ar += hv.x * wr[4*j] + hv.y * wr[4*j+1] + hv.z * wr[4*j+2] + hv.w * wr[4*j+3];
            az += hv.x * wz[4*j] + hv.y * wz[4*j+1] + hv.z * wz[4*j+2] + hv.w * wz[4*j+3];
            an += hv.x * wn[4*j] + hv.y * wn[4*j+1] + hv.z * wn[4*j+2] + hv.w * wn[4*j+3];
        }
        #pragma unroll
        for (int off = 16; off > 0; off >>= 1) {
            ar += __shfl_down(ar, off, 32);
            az += __shfl_down(az, off, 32);
            an += __shfl_down(an, off, 32);
        }

        if (i == 0) {
            const float r = 1.f / (1.f + expf(-(xr + ar)));
            const float z = 1.f / (1.f + expf(-(xz + az)));
            const float n = tanhf(xn + r * (an + bhn_c));
            const float hp = h_lds[col];
            const float hnew = (1.f - z) * n + z * hp;
            const unsigned long long packed =
                ((unsigned long long)(unsigned int)(t + 1) << 32) |
                (unsigned long long)__float_as_uint(hnew);
            __hip_atomic_store(dst + col, packed, __ATOMIC_RELAXED, __HIP_MEMORY_SCOPE_AGENT);
            ys[(size_t)t * Dh + col] = hnew;
        }
        // NOTE: no trailing __syncthreads needed — next iteration's poll can
        // only succeed after every group in every block (incl. this one) has
        // published t+1, which happens after their h_lds reads completed.
    }
}

// ---------------------------------------------------------------------------
// In-place layernorm over rows of y [T][Dh], matching jnp mean/var, eps=1e-6
// ---------------------------------------------------------------------------
__global__ __launch_bounds__(256)
void layernorm_ip(float* __restrict__ y, const float* __restrict__ sc,
                  const float* __restrict__ bi)
{
    __shared__ float red[8], red2[8], stat[2];
    const int row = blockIdx.x, tid = threadIdx.x;
    float4* yr = (float4*)(y + (size_t)row * Dh);
    float4 v = yr[tid];
    float s  = v.x + v.y + v.z + v.w;
    float s2 = v.x*v.x + v.y*v.y + v.z*v.z + v.w*v.w;
    #pragma unroll
    for (int off = 32; off > 0; off >>= 1) {
        s  += __shfl_down(s,  off);
        s2 += __shfl_down(s2, off);
    }
    if ((tid & 63) == 0) { red[tid >> 6] = s; red2[tid >> 6] = s2; }
    __syncthreads();
    if (tid == 0) {
        float ts = 0.f, t2 = 0.f;
        #pragma unroll
        for (int w = 0; w < 4; ++w) { ts += red[w]; t2 += red2[w]; }
        const float mu  = ts / (float)Dh;
        const float var = t2 / (float)Dh - mu * mu;
        stat[0] = mu;
        stat[1] = rsqrtf(var + 1e-6f);
    }
    __syncthreads();
    const float mu = stat[0], rstd = stat[1];
    const float4 s4 = ((const float4*)sc)[tid];
    const float4 b4 = ((const float4*)bi)[tid];
    v.x = (v.x - mu) * rstd * s4.x + b4.x;
    v.y = (v.y - mu) * rstd * s4.y + b4.y;
    v.z = (v.z - mu) * rstd * s4.z + b4.z;
    v.w = (v.w - mu) * rstd * s4.w + b4.w;
    yr[tid] = v;
}

// ---------------------------------------------------------------------------
extern "C" void kernel_launch(void* const* d_in, const int* in_sizes, int n_in,
                              void* d_out, int out_size, void* d_ws, size_t ws_size,
                              hipStream_t stream)
{
    const float* xs   = (const float*)d_in[0];
    const float* h0   = (const float*)d_in[1];
    const float* Wir  = (const float*)d_in[2];
    const float* Wiz  = (const float*)d_in[3];
    const float* Win  = (const float*)d_in[4];
    const float* bir  = (const float*)d_in[5];
    const float* biz  = (const float*)d_in[6];
    const float* bin_ = (const float*)d_in[7];
    const float* Whr  = (const float*)d_in[8];
    const float* Whz  = (const float*)d_in[9];
    const float* Whn  = (const float*)d_in[10];
    const float* bhn  = (const float*)d_in[11];
    const float* Wl   = (const float*)d_in[12];
    const float* bl   = (const float*)d_in[13];
    const float* ln_s = (const float*)d_in[14];
    const float* ln_b = (const float*)d_in[15];
    float* out = (float*)d_out;

    // workspace layout
    float* xproj = (float*)d_ws;                               // T*3*Dh
    float* ys    = xproj + (size_t)Tt * 3 * Dh;                // T*Dh
    unsigned long long* hbuf = (unsigned long long*)(ys + (size_t)Tt * Dh); // 2*Dh packed

    // Phase 0: pack init state with tag 0 into buf[0]
    pack_h0<<<4, 256, 0, stream>>>(h0, hbuf);

    // Phase 1: input projections (bias folded in)
    dim3 ggrid(Dh / 64, Tt / 64);
    gemm64<false, false><<<ggrid, 256, 0, stream>>>(xs, Wir, bir, nullptr,
                                                    xproj + 0 * Dh, Tt, Dh, Dh, 3 * Dh);
    gemm64<false, false><<<ggrid, 256, 0, stream>>>(xs, Wiz, biz, nullptr,
                                                    xproj + 1 * Dh, Tt, Dh, Dh, 3 * Dh);
    gemm64<false, false><<<ggrid, 256, 0, stream>>>(xs, Win, bin_, nullptr,
                                                    xproj + 2 * Dh, Tt, Dh, Dh, 3 * Dh);

    // Phase 2: sequential scan (persistent, co-resident grid)
    gru_rec<<<NB, 256, 0, stream>>>(xproj, Whr, Whz, Whn, bhn, ys, hbuf);

    // Phase 3: out = relu(ys) @ Wl + bl + xs, then in-place layernorm
    gemm64<true, true><<<ggrid, 256, 0, stream>>>(ys, Wl, bl, xs, out, Tt, Dh, Dh, Dh);
    layernorm_ip<<<Tt, 256, 0, stream>>>(out, ln_s, ln_b);
}

// Round 3
// 10570.190 us; speedup vs baseline: 4.3723x; 1.0949x over previous
//
#include <hip/hip_runtime.h>
#include <math.h>

#define Dh 1024
#define Tt 4096
#define NB 128   // recurrence blocks; each owns 8 output columns

// ---------------------------------------------------------------------------
// GEMM: C[M x N](ldc) = op(A[M x K]) @ B[K x N] + bias [+ resid]
// 64x64 tile, BK=16, 256 threads, 4x4 micro-tile per thread. fp32.
// ---------------------------------------------------------------------------
template<bool RELU, bool RESID>
__global__ __launch_bounds__(256)
void gemm64(const float* __restrict__ A, const float* __restrict__ B,
            const float* __restrict__ bias, const float* __restrict__ resid,
            float* __restrict__ C, int M, int N, int K, int ldc)
{
    __shared__ __align__(16) float As[16][68];   // [k][m], padded row
    __shared__ __align__(16) float Bs[16][64];   // [k][n]
    const int tid = threadIdx.x;
    const int tx = tid & 15, ty = tid >> 4;
    const int bn = blockIdx.x * 64, bm = blockIdx.y * 64;

    const int lm = tid >> 2, lk = (tid & 3) * 4;     // A tile load coords
    const int bk = tid >> 4, bn4 = (tid & 15) * 4;   // B tile load coords

    float acc[4][4] = {};

    for (int k0 = 0; k0 < K; k0 += 16) {
        float4 av = *(const float4*)(A + (size_t)(bm + lm) * K + k0 + lk);
        if (RELU) {
            av.x = fmaxf(av.x, 0.f); av.y = fmaxf(av.y, 0.f);
            av.z = fmaxf(av.z, 0.f); av.w = fmaxf(av.w, 0.f);
        }
        As[lk + 0][lm] = av.x; As[lk + 1][lm] = av.y;
        As[lk + 2][lm] = av.z; As[lk + 3][lm] = av.w;
        *(float4*)&Bs[bk][bn4] = *(const float4*)(B + (size_t)(k0 + bk) * N + bn + bn4);
        __syncthreads();
        #pragma unroll
        for (int kk = 0; kk < 16; ++kk) {
            float4 a4 = *(const float4*)&As[kk][ty * 4];
            float4 b4 = *(const float4*)&Bs[kk][tx * 4];
            acc[0][0] += a4.x * b4.x; acc[0][1] += a4.x * b4.y; acc[0][2] += a4.x * b4.z; acc[0][3] += a4.x * b4.w;
            acc[1][0] += a4.y * b4.x; acc[1][1] += a4.y * b4.y; acc[1][2] += a4.y * b4.z; acc[1][3] += a4.y * b4.w;
            acc[2][0] += a4.z * b4.x; acc[2][1] += a4.z * b4.y; acc[2][2] += a4.z * b4.z; acc[2][3] += a4.z * b4.w;
            acc[3][0] += a4.w * b4.x; acc[3][1] += a4.w * b4.y; acc[3][2] += a4.w * b4.z; acc[3][3] += a4.w * b4.w;
        }
        __syncthreads();
    }

    const float4 bias4 = *(const float4*)(bias + bn + tx * 4);
    #pragma unroll
    for (int i = 0; i < 4; ++i) {
        const int row = bm + ty * 4 + i;
        float4 o;
        o.x = acc[i][0] + bias4.x; o.y = acc[i][1] + bias4.y;
        o.z = acc[i][2] + bias4.z; o.w = acc[i][3] + bias4.w;
        if (RESID) {
            const float4 r4 = *(const float4*)(resid + (size_t)row * N + bn + tx * 4);
            o.x += r4.x; o.y += r4.y; o.z += r4.z; o.w += r4.w;
        }
        *(float4*)(C + (size_t)row * ldc + bn + tx * 4) = o;
    }
}

// ---------------------------------------------------------------------------
// Fast activations — tolerance is 0.099 absmax; native exp/rcp are ~1e-6 rel.
// ---------------------------------------------------------------------------
__device__ __forceinline__ float fast_sigmoid(float x)
{
    // 1/(1+e^-x); e^-x -> inf for very negative x gives rcp(inf)=0: correct.
    return __builtin_amdgcn_rcpf(1.f + __expf(-x));
}
__device__ __forceinline__ float fast_tanh(float x)
{
    x = fminf(15.f, fmaxf(-15.f, x));        // keep exp finite
    const float e2 = __expf(2.f * x);
    return (e2 - 1.f) * __builtin_amdgcn_rcpf(e2 + 1.f);
}

// ---------------------------------------------------------------------------
// Pack init_state into epoch-tagged slots: {tag=0 : value} in buf[0]
// ---------------------------------------------------------------------------
__global__ __launch_bounds__(256)
void pack_h0(const float* __restrict__ h0, unsigned long long* __restrict__ buf)
{
    const int idx = blockIdx.x * 256 + threadIdx.x;   // 0..1023
    __hip_atomic_store(buf + idx, (unsigned long long)__float_as_uint(h0[idx]),
                       __ATOMIC_RELAXED, __HIP_MEMORY_SCOPE_AGENT);
}

// ---------------------------------------------------------------------------
// Sequential GRU scan. 128 blocks x 256 threads, all co-resident.
// Block b owns output columns [8b, 8b+8); each column = one 32-lane group.
// Weights register/AGPR-resident (96 floats/thread).
// Sync: h entries are {tag,value} 64-bit atomics; consumers poll tags.
// Critical-path hygiene: ys stores delayed one step (write-ack off the poll's
// vmcnt), xproj prefetched one step ahead, native activations.
// ---------------------------------------------------------------------------
__global__ __launch_bounds__(256, 1)
void gru_rec(const float* __restrict__ xproj,   // [T][3*Dh]  (r,z,n) incl. input bias
             const float* __restrict__ Whr, const float* __restrict__ Whz,
             const float* __restrict__ Whn, const float* __restrict__ bhn,
             float* __restrict__ ys,            // [T][Dh]
             unsigned long long* __restrict__ hbuf)  // [2][Dh] packed {tag,val}
{
    const int b = blockIdx.x, tid = threadIdx.x;
    const int g = tid >> 5;        // group 0..7 -> local column
    const int i = tid & 31;        // lane in group
    const int col = b * 8 + g;

    __shared__ __align__(16) float h_lds[Dh];

    // Register-resident weight slice: rows r = 4i + 128j + k
    float wr[32], wz[32], wn[32];
    #pragma unroll
    for (int j = 0; j < 8; ++j)
        #pragma unroll
        for (int k = 0; k < 4; ++k) {
            const int r = 4 * i + 128 * j + k;
            wr[j * 4 + k] = Whr[(size_t)r * Dh + col];
            wz[j * 4 + k] = Whz[(size_t)r * Dh + col];
            wn[j * 4 + k] = Whn[(size_t)r * Dh + col];
        }
    const float bhn_c = bhn[col];

    // xproj prefetch registers (one step ahead)
    float xr_n = 0.f, xz_n = 0.f, xn_n = 0.f;
    if (i == 0) {
        xr_n = xproj[col]; xz_n = xproj[Dh + col]; xn_n = xproj[2 * Dh + col];
    }
    float y_prev = 0.f;

    for (int t = 0; t < Tt; ++t) {
        const unsigned long long* src = hbuf + (size_t)(t & 1) * Dh;
        unsigned long long*       dst = hbuf + (size_t)((t + 1) & 1) * Dh;
        const unsigned int want = (unsigned int)t;

        // rotate prefetched xproj; issue next step's loads (full step to land)
        const float xr = xr_n, xz = xz_n, xn = xn_n;
        if (i == 0 && t + 1 < Tt) {
            const float* xp = xproj + (size_t)(t + 1) * (3 * Dh);
            xr_n = xp[col]; xz_n = xp[Dh + col]; xn_n = xp[2 * Dh + col];
        }

        // poll this thread's 4 packed entries until their tags reach t
        unsigned long long p0, p1, p2, p3;
        int tries = 0;
        for (;;) {
            p0 = __hip_atomic_load(src + tid +   0, __ATOMIC_RELAXED, __HIP_MEMORY_SCOPE_AGENT);
            p1 = __hip_atomic_load(src + tid + 256, __ATOMIC_RELAXED, __HIP_MEMORY_SCOPE_AGENT);
            p2 = __hip_atomic_load(src + tid + 512, __ATOMIC_RELAXED, __HIP_MEMORY_SCOPE_AGENT);
            p3 = __hip_atomic_load(src + tid + 768, __ATOMIC_RELAXED, __HIP_MEMORY_SCOPE_AGENT);
            unsigned int bad = ((unsigned int)(p0 >> 32)) ^ want;
            bad |= ((unsigned int)(p1 >> 32)) ^ want;
            bad |= ((unsigned int)(p2 >> 32)) ^ want;
            bad |= ((unsigned int)(p3 >> 32)) ^ want;
            if (!bad) break;
            if (++tries > 3) __builtin_amdgcn_s_sleep(1);
        }

        // delayed ys store for step t-1: ack hides under this whole step
        if (i == 0 && t > 0) ys[(size_t)(t - 1) * Dh + col] = y_prev;

        h_lds[tid +   0] = __uint_as_float((unsigned int)p0);
        h_lds[tid + 256] = __uint_as_float((unsigned int)p1);
        h_lds[tid + 512] = __uint_as_float((unsigned int)p2);
        h_lds[tid + 768] = __uint_as_float((unsigned int)p3);
        __syncthreads();   // also guarantees all polls of src are done before
                           // any group can publish t+1 (buffer-reuse safety)

        float ar = 0.f, az = 0.f, an = 0.f;
        const float4* h4 = (const float4*)h_lds;
        #pragma unroll
        for (int j = 0; j < 8; ++j) {
            const float4 hv = h4[i + j * 32];
            ar += hv.x * wr[4*j] + hv.y * wr[4*j+1] + hv.z * wr[4*j+2] + hv.w * wr[4*j+3];
            az += hv.x * wz[4*j] + hv.y * wz[4*j+1] + hv.z * wz[4*j+2] + hv.w * wz[4*j+3];
            an += hv.x * wn[4*j] + hv.y * wn[4*j+1] + hv.z * wn[4*j+2] + hv.w * wn[4*j+3];
        }
        #pragma unroll
        for (int off = 16; off > 0; off >>= 1) {
            ar += __shfl_down(ar, off, 32);
            az += __shfl_down(az, off, 32);
            an += __shfl_down(an, off, 32);
        }

        if (i == 0) {
            const float r = fast_sigmoid(xr + ar);
            const float z = fast_sigmoid(xz + az);
            const float n = fast_tanh(xn + r * (an + bhn_c));
            const float hp = h_lds[col];
            const float hnew = (1.f - z) * n + z * hp;
            const unsigned long long packed =
                ((unsigned long long)(unsigned int)(t + 1) << 32) |
                (unsigned long long)__float_as_uint(hnew);
            __hip_atomic_store(dst + col, packed, __ATOMIC_RELAXED, __HIP_MEMORY_SCOPE_AGENT);
            y_prev = hnew;
        }
    }
    if (i == 0) ys[(size_t)(Tt - 1) * Dh + col] = y_prev;   // final delayed store
}

// ---------------------------------------------------------------------------
// In-place layernorm over rows of y [T][Dh], matching jnp mean/var, eps=1e-6
// ---------------------------------------------------------------------------
__global__ __launch_bounds__(256)
void layernorm_ip(float* __restrict__ y, const float* __restrict__ sc,
                  const float* __restrict__ bi)
{
    __shared__ float red[8], red2[8], stat[2];
    const int row = blockIdx.x, tid = threadIdx.x;
    float4* yr = (float4*)(y + (size_t)row * Dh);
    float4 v = yr[tid];
    float s  = v.x + v.y + v.z + v.w;
    float s2 = v.x*v.x + v.y*v.y + v.z*v.z + v.w*v.w;
    #pragma unroll
    for (int off = 32; off > 0; off >>= 1) {
        s  += __shfl_down(s,  off);
        s2 += __shfl_down(s2, off);
    }
    if ((tid & 63) == 0) { red[tid >> 6] = s; red2[tid >> 6] = s2; }
    __syncthreads();
    if (tid == 0) {
        float ts = 0.f, t2 = 0.f;
        #pragma unroll
        for (int w = 0; w < 4; ++w) { ts += red[w]; t2 += red2[w]; }
        const float mu  = ts / (float)Dh;
        const float var = t2 / (float)Dh - mu * mu;
        stat[0] = mu;
        stat[1] = rsqrtf(var + 1e-6f);
    }
    __syncthreads();
    const float mu = stat[0], rstd = stat[1];
    const float4 s4 = ((const float4*)sc)[tid];
    const float4 b4 = ((const float4*)bi)[tid];
    v.x = (v.x - mu) * rstd * s4.x + b4.x;
    v.y = (v.y - mu) * rstd * s4.y + b4.y;
    v.z = (v.z - mu) * rstd * s4.z + b4.z;
    v.w = (v.w - mu) * rstd * s4.w + b4.w;
    yr[tid] = v;
}

// ---------------------------------------------------------------------------
extern "C" void kernel_launch(void* const* d_in, const int* in_sizes, int n_in,
                              void* d_out, int out_size, void* d_ws, size_t ws_size,
                              hipStream_t stream)
{
    const float* xs   = (const float*)d_in[0];
    const float* h0   = (const float*)d_in[1];
    const float* Wir  = (const float*)d_in[2];
    const float* Wiz  = (const float*)d_in[3];
    const float* Win  = (const float*)d_in[4];
    const float* bir  = (const float*)d_in[5];
    const float* biz  = (const float*)d_in[6];
    const float* bin_ = (const float*)d_in[7];
    const float* Whr  = (const float*)d_in[8];
    const float* Whz  = (const float*)d_in[9];
    const float* Whn  = (const float*)d_in[10];
    const float* bhn  = (const float*)d_in[11];
    const float* Wl   = (const float*)d_in[12];
    const float* bl   = (const float*)d_in[13];
    const float* ln_s = (const float*)d_in[14];
    const float* ln_b = (const float*)d_in[15];
    float* out = (float*)d_out;

    // workspace layout
    float* xproj = (float*)d_ws;                               // T*3*Dh
    float* ys    = xproj + (size_t)Tt * 3 * Dh;                // T*Dh
    unsigned long long* hbuf = (unsigned long long*)(ys + (size_t)Tt * Dh); // 2*Dh packed

    // Phase 0: pack init state with tag 0 into buf[0]
    pack_h0<<<4, 256, 0, stream>>>(h0, hbuf);

    // Phase 1: input projections (bias folded in)
    dim3 ggrid(Dh / 64, Tt / 64);
    gemm64<false, false><<<ggrid, 256, 0, stream>>>(xs, Wir, bir, nullptr,
                                                    xproj + 0 * Dh, Tt, Dh, Dh, 3 * Dh);
    gemm64<false, false><<<ggrid, 256, 0, stream>>>(xs, Wiz, biz, nullptr,
                                                    xproj + 1 * Dh, Tt, Dh, Dh, 3 * Dh);
    gemm64<false, false><<<ggrid, 256, 0, stream>>>(xs, Win, bin_, nullptr,
                                                    xproj + 2 * Dh, Tt, Dh, Dh, 3 * Dh);

    // Phase 2: sequential scan (persistent, co-resident grid)
    gru_rec<<<NB, 256, 0, stream>>>(xproj, Whr, Whz, Whn, bhn, ys, hbuf);

    // Phase 3: out = relu(ys) @ Wl + bl + xs, then in-place layernorm
    gemm64<true, true><<<ggrid, 256, 0, stream>>>(ys, Wl, bl, xs, out, Tt, Dh, Dh, Dh);
    layernorm_ip<<<Tt, 256, 0, stream>>>(out, ln_s, ln_b);
}